// Round 12
// baseline (164.052 us; speedup 1.0000x reference)
//
#include <hip/hip_runtime.h>

typedef __attribute__((ext_vector_type(8))) short bf16x8;
typedef __attribute__((ext_vector_type(4))) float f32x4;
typedef __attribute__((ext_vector_type(4))) unsigned short us4;

#define NBATCH 64
#define NFEAT  64
#define NSITES 1024
#define NSYMM  1024
#define NINF   4
#define BN     128          // k-tile per workgroup
#define XSTR   1160         // LDS elems per x-copy slot (2320 B)

static __device__ __forceinline__ unsigned short f2bf(float f) {
  union { float f; unsigned int u; } v; v.f = f;
  unsigned int u = v.u;
  return (unsigned short)((u + 0x7fffu + ((u >> 16) & 1u)) >> 16);  // RNE
}

// ---------------- single fused kernel: NO workspace, no prepass -------------------------
// 512 blocks (2/CU), 4 waves. Wave wv owns l-subchunk wv*32 of each 128-l step tile and
// computes the full m64 x k128 tile as an l-partial (acc[4][8]).
//  - x: staged per j into xc LDS (8 shifted bf16 copies) from raw fp32 with in-kernel RNE
//    cvt; 2 barriers per j-boundary (x3).
//  - w: A-frags loaded straight from fp32 ker (L2-resident; each block reads ker once),
//    double-buffered in raw f32 regs one step ahead, cvt'd to bf16 at use (VALU pipe,
//    co-issues under the MFMA cluster).
//  - epilogue: cross-wave l-reduction via LDS (red overlays xc).
__global__ __launch_bounds__(256, 2)
void dense_symm_fused(const float* __restrict__ x,
                      const float* __restrict__ ker,
                      const float* __restrict__ bias,
                      float* __restrict__ out)
{
  __shared__ __align__(16) char shmem[32768];    // max(xc 18.1 KB, red 32 KB)
  unsigned short* xc = (unsigned short*)shmem;
  float*          red = (float*)shmem;

  const int tid  = threadIdx.x;   // 0..255
  const int lane = tid & 63;
  const int wv   = tid >> 6;      // 0..3; wave owns l-subchunk wv*32
  const int wg   = blockIdx.x;
  const int i    = wg >> 3;
  const int k0   = (wg & 7) * BN;

  f32x4 acc[4][8];                // [mf][f] — m64 x k128 l-partial
  #pragma unroll
  for (int mf = 0; mf < 4; ++mf)
    #pragma unroll
    for (int f = 0; f < 8; ++f) acc[mf][f] = (f32x4)0.f;

  const int akk = (lane >> 4) << 3;               // l-offset within the 32-l chunk
  const int c   = lane & 7;                       // which shifted copy
  const int pb  = akk + (((lane >> 3) & 1) << 3); // B addr: p = l0 + f*16 + pb (+s)
  const int am  = lane & 15;                      // A row within fragment

  // stage xc for in-feature jj: xc[cc*XSTR + p] = bf16(x[i][jj][(p+cc+k0)&1023]),
  // cc in [0,8), p in [0,1152). 2304 quads / 256 threads = 9 per thread.
  auto stage_x = [&](int jj) {
    const float* xr = x + (i * NINF + jj) * NSITES;
    #pragma unroll
    for (int r = 0; r < 9; ++r) {
      int q  = r * 256 + tid;            // 0..2303
      int cc = q / 288;                  // 0..7   (288 quads per copy)
      int p4 = (q - cc * 288) << 2;      // 0..1148
      int b0 = p4 + cc + k0;
      us4 h;
      h.x = f2bf(xr[(b0)     & 1023]);
      h.y = f2bf(xr[(b0 + 1) & 1023]);
      h.z = f2bf(xr[(b0 + 2) & 1023]);
      h.w = f2bf(xr[(b0 + 3) & 1023]);
      *(us4*)&xc[cc * XSTR + p4] = h;    // ds_write_b64
    }
  };

  // A raw loads for step s: per mf, 8 consecutive f32 of row m = mf*16+am at
  // l = lt*128 + wv*32 + akk (32 B contiguous per lane).
  f32x4 araw[8];                          // [mf*2 + half]
  auto loadAraw = [&](int s) {
    int jj = s >> 3, lt = s & 7;
    int l  = lt * 128 + wv * 32 + akk;
    #pragma unroll
    for (int mf = 0; mf < 4; ++mf) {
      const float* p = &ker[((mf * 16 + am) * NINF + jj) * NSITES + l];
      araw[mf * 2]     = *(const f32x4*)p;
      araw[mf * 2 + 1] = *(const f32x4*)(p + 4);
    }
  };

  // --- prologue: xc(j=0) + araw = A(0) ---
  stage_x(0);
  loadAraw(0);
  __syncthreads();                        // xc ready; araw(0) landed

  bf16x8 abf[4];
  #pragma unroll
  for (int j = 0; j < 4; ++j) {
    if (j > 0) {
      __syncthreads();                    // all xc reads for j-1 done
      stage_x(j);
      __syncthreads();                    // new xc visible
    }
    const unsigned short* xcc = &xc[c * XSTR];
    #pragma unroll
    for (int lt = 0; lt < 8; ++lt) {
      const int step = j * 8 + lt;

      // cvt araw (loaded one step ago) -> bf16 fragments for THIS step
      #pragma unroll
      for (int mf = 0; mf < 4; ++mf) {
        bf16x8 t;
        #pragma unroll
        for (int e = 0; e < 4; ++e) {
          t[e]     = (short)f2bf(araw[mf * 2][e]);
          t[e + 4] = (short)f2bf(araw[mf * 2 + 1][e]);
        }
        abf[mf] = t;
      }
      // issue NEXT step's raw A loads (overwrites araw after cvt consumed it)
      if (step < 31) loadAraw(step + 1);

      const int l0 = lt * 128 + wv * 32;
      bf16x8 bfr[8];                      // hoist ALL B reads before MFMA cluster
      #pragma unroll
      for (int f = 0; f < 8; ++f)
        bfr[f] = *(const bf16x8*)&xcc[l0 + f * 16 + pb];

      __builtin_amdgcn_s_setprio(1);
      #pragma unroll
      for (int f = 0; f < 8; ++f)
        #pragma unroll
        for (int mf = 0; mf < 4; ++mf)
          acc[mf][f] = __builtin_amdgcn_mfma_f32_16x16x32_bf16(abf[mf], bfr[f], acc[mf][f], 0, 0, 0);
      __builtin_amdgcn_s_setprio(0);
    }
  }

  // --- epilogue: cross-wave l-reduction via LDS (red overlays xc) ----------------------
  // C/D layout col=lane&15, row=(lane>>4)*4+reg [m89]; lane-aligned across waves.
  const int col = lane & 15;
  const int rb  = (lane >> 4) << 2;
  #pragma unroll
  for (int mf = 0; mf < 4; ++mf) {
    __syncthreads();                      // xc reads (mf=0) / prev red reads (mf>0) done
    #pragma unroll
    for (int f = 0; f < 8; ++f)
      *(f32x4*)&red[(((wv << 3) + f) << 6 | lane) << 2] = acc[mf][f];
    __syncthreads();
    #pragma unroll
    for (int fo = 0; fo < 2; ++fo) {      // wave wv reduces f-range [2*wv, 2*wv+2)
      int f = (wv << 1) + fo;
      f32x4 s0 = *(const f32x4*)&red[((0 * 8 + f) << 6 | lane) << 2];
      f32x4 s1 = *(const f32x4*)&red[((1 * 8 + f) << 6 | lane) << 2];
      f32x4 s2 = *(const f32x4*)&red[((2 * 8 + f) << 6 | lane) << 2];
      f32x4 s3 = *(const f32x4*)&red[((3 * 8 + f) << 6 | lane) << 2];
      #pragma unroll
      for (int r = 0; r < 4; ++r) {
        int m = mf * 16 + rb + r;
        int k = k0 + f * 16 + col;
        out[(i * NFEAT + m) * NSYMM + k] = s0[r] + s1[r] + s2[r] + s3[r] + bias[m];
      }
    }
  }
}

extern "C" void kernel_launch(void* const* d_in, const int* in_sizes, int n_in,
                              void* d_out, int out_size, void* d_ws, size_t ws_size,
                              hipStream_t stream) {
  const float* x    = (const float*)d_in[0];
  // d_in[1] = symm (cyclic translations by construction) — unused
  const float* ker  = (const float*)d_in[2];
  const float* bias = (const float*)d_in[3];
  float* out = (float*)d_out;
  // Workspace intentionally unused: avoids the ~45 us 256 MiB d_ws re-poison fill in the
  // timed window (and the prepass dispatch + inter-kernel gap).
  dense_symm_fused<<<dim3(512), dim3(256), 0, stream>>>(x, ker, bias, out);
}

// Round 13
// 107.165 us; speedup vs baseline: 1.5308x; 1.5308x over previous
//
#include <hip/hip_runtime.h>

typedef __attribute__((ext_vector_type(8))) short bf16x8;
typedef __attribute__((ext_vector_type(4))) float f32x4;
typedef __attribute__((ext_vector_type(4))) unsigned short us4;

#define NBATCH 64
#define NFEAT  64
#define NSITES 1024
#define NSYMM  1024
#define NINF   4
#define BN     128          // k-tile per workgroup
#define XSTR   1160         // LDS elems per x-copy slot (2320 B)

static __device__ __forceinline__ unsigned short f2bf(float f) {
  union { float f; unsigned int u; } v; v.f = f;
  unsigned int u = v.u;
  return (unsigned short)((u + 0x7fffu + ((u >> 16) & 1u)) >> 16);  // RNE
}

#define GLDS16(g, l) \
  __builtin_amdgcn_global_load_lds((const __attribute__((address_space(1))) unsigned int*)(g), \
                                   (__attribute__((address_space(3))) unsigned int*)(l), 16, 0, 0)
#define GLDS4(g, l) \
  __builtin_amdgcn_global_load_lds((const __attribute__((address_space(1))) unsigned int*)(g), \
                                   (__attribute__((address_space(3))) unsigned int*)(l), 4, 0, 0)

// ---------------- fused prepass (identical to round 10) ---------------------------------
// blocks [0,128):    w -> bf16 REGISTER-FRAGMENT blobs: for step=(j*8+lt), l-chunk q(32),
//                    lane, mf: 8 elems w[m = mf*16 + (lane&15)][l = lt*128 + q*32 + ((lane>>4)<<3) + s]
//                    at wprep[(((step*4+q)*64+lane)*4+mf)*8 + s].
// blocks [128,2176): x -> bf16, 8 shifted copies, 2048-wide window:
//                    xshift[i][j][c][p] = bf16(x[i][j][(p+c) & 1023])
__global__ void prep_all(const float* __restrict__ x, const float* __restrict__ ker,
                         unsigned short* __restrict__ wprep, unsigned short* __restrict__ xshift) {
  int b = blockIdx.x;
  if (b < 128) {
    int t = b * 256 + threadIdx.x;          // 0..32767, one 16B blob each
    int mf = t & 3, lane = (t >> 2) & 63, q = (t >> 8) & 3, step = t >> 10;
    int j = step >> 3, lt = step & 7;
    int m = mf * 16 + (lane & 15);
    int l = lt * 128 + q * 32 + ((lane >> 4) << 3);
    const float* kp = &ker[(m * NINF + j) * NSITES + l];
    const float4 v0 = *(const float4*)kp;
    const float4 v1 = *(const float4*)(kp + 4);
    us4 h0, h1;
    h0.x = f2bf(v0.x); h0.y = f2bf(v0.y); h0.z = f2bf(v0.z); h0.w = f2bf(v0.w);
    h1.x = f2bf(v1.x); h1.y = f2bf(v1.y); h1.z = f2bf(v1.z); h1.w = f2bf(v1.w);
    *(us4*)&wprep[t * 8]     = h0;
    *(us4*)&wprep[t * 8 + 4] = h1;
  } else {
    int bb = b - 128;
    int ij = bb >> 3, cc = bb & 7;
    const float* xr = x + ij * NSITES;
    unsigned short* dst = xshift + (size_t)(ij * 8 + cc) * 2048;
    #pragma unroll
    for (int r = 0; r < 2; ++r) {
      int p = (r * 256 + threadIdx.x) << 2;
      us4 h;
      h.x = f2bf(xr[(p + cc)     & 1023]);
      h.y = f2bf(xr[(p + cc + 1) & 1023]);
      h.z = f2bf(xr[(p + cc + 2) & 1023]);
      h.w = f2bf(xr[(p + cc + 3) & 1023]);
      *(us4*)&dst[p] = h;
    }
  }
}

// ---------------- main kernel: hybrid 2l x 2k wave split --------------------------------
// 512 blocks (2/CU), 4 waves = (wl, wk). Wave computes m64 x k64 (k-half wk) restricted to
// l-half wl of each 128-l step tile (2 ks-slices of 32). acc[4][4] = 64 VGPR. A-frags
// stream global->VGPR double-buffered; B-frags from xc LDS (double-buffered per j, stage
// for j+1 issued at start of j; ONE barrier per j). Epilogue: wl=1 waves write partials
// to LDS (red overlays xc2), ONE barrier, wl=0 waves add + store.
__global__ __launch_bounds__(256, 2)
void dense_symm_main(const unsigned short* __restrict__ wprep,
                     const unsigned short* __restrict__ xshift,
                     const float* __restrict__ bias,
                     float* __restrict__ out)
{
  __shared__ unsigned short xc2[2][8 * XSTR];  // 2 x 18.1 KB, double-buffered x copies
  float* red = (float*)&xc2[0][0];             // 32 KB epilogue buffer overlays xc2

  const int tid  = threadIdx.x;   // 0..255
  const int lane = tid & 63;
  const int wv   = tid >> 6;      // 0..3
  const int wl   = wv >> 1;       // l-half of each step tile
  const int wk   = wv & 1;        // k-half of the 128-k block tile
  const int wg   = blockIdx.x;
  const int i    = wg >> 3;
  const int k0   = (wg & 7) * BN;

  f32x4 acc[4][4];                // [mf][f] — m64 x k64 partial over this wave's l-half
  #pragma unroll
  for (int mf = 0; mf < 4; ++mf)
    #pragma unroll
    for (int f = 0; f < 4; ++f) acc[mf][f] = (f32x4)0.f;

  const int akk = (lane >> 4) << 3;               // l-offset within a 32-l ks-slice
  const int c   = lane & 7;                       // which shifted copy
  const int pb  = akk + (((lane >> 3) & 1) << 3); // B addr: p = l0 + ks*32 + wk*64 + f*16 + pb

  auto stage_x_chunk = [&](int buf, int jj, int c3) {  // c3 in [0,24): copy=c3/3, part=c3%3
    int cc = c3 / 3, part = c3 % 3;
    const char* src = (const char*)(xshift + (((i * 4 + jj) * 8 + cc) << 11) + k0);
    char* dst = (char*)&xc2[buf][0] + cc * (XSTR * 2);
    if (part < 2) GLDS16(src + part * 1024 + lane * 16, dst + part * 1024);
    else          GLDS4(src + 2048 + lane * 4, dst + 2048);
  };

  // A blobs: chunk = wl*2 + ks; elem offset ((step*4 + chunk)*64 + lane)*32 + mf*8
  auto loadA = [&](bf16x8 (*dst)[4], int s) {
    #pragma unroll
    for (int ks = 0; ks < 2; ++ks) {
      const unsigned short* p =
          wprep + (((size_t)(s * 4 + wl * 2 + ks) << 11) | ((size_t)lane << 5));
      #pragma unroll
      for (int mf = 0; mf < 4; ++mf) dst[ks][mf] = *(const bf16x8*)(p + mf * 8);
    }
  };

  // --- prologue: xc buf0 (j=0) + A(step 0) ---
  for (int r = 0; r < 6; ++r) stage_x_chunk(0, 0, wv * 6 + r);
  bf16x8 a0[2][4], a1[2][4];
  loadA(a0, 0);
  __syncthreads();                                // drains vmcnt(0): buf0 + a0 ready

  #pragma unroll
  for (int j = 0; j < 4; ++j) {
    // issue next j's xc stage into the other buffer (overlaps this j's compute)
    if (j < 3)
      for (int r = 0; r < 6; ++r) stage_x_chunk((j + 1) & 1, j + 1, wv * 6 + r);

    const unsigned short* xcc = &xc2[j & 1][c * XSTR];
    #pragma unroll
    for (int lt = 0; lt < 8; ++lt) {              // full unroll -> a0/a1 select is static
      const int step = j * 8 + lt;
      bf16x8 (*acur)[4] = (lt & 1) ? a1 : a0;
      bf16x8 (*anxt)[4] = (lt & 1) ? a0 : a1;
      if (step < 31) loadA(anxt, step + 1);       // prefetch next step's A into regs

      const int l0 = lt * 128 + wl * 64;
      bf16x8 bfr[2][4];                           // hoist ALL B reads before MFMA cluster
      #pragma unroll
      for (int ks = 0; ks < 2; ++ks)
        #pragma unroll
        for (int f = 0; f < 4; ++f)
          bfr[ks][f] = *(const bf16x8*)&xcc[l0 + ks * 32 + wk * 64 + f * 16 + pb];

      __builtin_amdgcn_s_setprio(1);
      #pragma unroll
      for (int ks = 0; ks < 2; ++ks)
        #pragma unroll
        for (int f = 0; f < 4; ++f)
          #pragma unroll
          for (int mf = 0; mf < 4; ++mf)
            acc[mf][f] = __builtin_amdgcn_mfma_f32_16x16x32_bf16(acur[ks][mf], bfr[ks][f], acc[mf][f], 0, 0, 0);
      __builtin_amdgcn_s_setprio(0);
    }
    __syncthreads();                              // j-boundary: drain stage, swap buffers
  }

  // --- epilogue: 2-way l-reduction; wl=1 writes, wl=0 adds + stores --------------------
  // C/D layout col=lane&15, row=(lane>>4)*4+reg [m89]; lane-aligned across waves.
  const int col = lane & 15;
  const int rb  = (lane >> 4) << 2;
  if (wl == 1) {
    #pragma unroll
    for (int mf = 0; mf < 4; ++mf)
      #pragma unroll
      for (int f = 0; f < 4; ++f)
        *(f32x4*)&red[(((wk * 16 + mf * 4 + f) << 6) | lane) << 2] = acc[mf][f];
  }
  __syncthreads();
  if (wl == 0) {
    #pragma unroll
    for (int mf = 0; mf < 4; ++mf)
      #pragma unroll
      for (int f = 0; f < 4; ++f) {
        f32x4 s = *(const f32x4*)&red[(((wk * 16 + mf * 4 + f) << 6) | lane) << 2];
        #pragma unroll
        for (int r = 0; r < 4; ++r) {
          int m = mf * 16 + rb + r;
          int k = k0 + wk * 64 + f * 16 + col;
          out[(i * NFEAT + m) * NSYMM + k] = acc[mf][f][r] + s[r] + bias[m];
        }
      }
  }
}

// ---------------- fallback (round-1 kernel, used only if ws_size too small) -------------
#define BL 128
#define WSTR 136
__global__ __launch_bounds__(256, 2)
void dense_symm_kernel(const float* __restrict__ x,
                       const float* __restrict__ ker,
                       const float* __restrict__ bias,
                       float* __restrict__ out)
{
  __shared__ unsigned short xcp[8 * XSTR];
  __shared__ unsigned short wS[64 * WSTR];
  const int tid  = threadIdx.x;
  const int lane = tid & 63;
  const int wv   = tid >> 6;
  const int wg   = blockIdx.x;
  const int i    = wg >> 3;
  const int k0   = (wg & 7) * BN;
  f32x4 acc[4][2];
  for (int mf = 0; mf < 4; ++mf)
    for (int f = 0; f < 2; ++f) acc[mf][f] = (f32x4)0.f;
  const int arow   = lane & 15;
  const int akk    = (lane >> 4) << 3;
  const int c      = lane & 7;
  const int pbase0 = wv * 32 + akk + (((lane >> 3) & 1) << 3);
  for (int j = 0; j < NINF; ++j) {
    __syncthreads();
    const float* xrow = x + (i * NINF + j) * NSITES;
    for (int cc = 0; cc < 8; ++cc)
      for (int p = tid; p < NSITES + BN; p += 256)
        xcp[cc * XSTR + p] = f2bf(xrow[(p + cc + k0) & (NSITES - 1)]);
    for (int lt = 0; lt < NSITES / BL; ++lt) {
      __syncthreads();
      for (int u = 0; u < 8; ++u) {
        int q = u * 256 + tid;
        int m = q >> 5, c4 = q & 31;
        const float4 v = *(const float4*)&ker[(m * NINF + j) * NSITES + lt * BL + (c4 << 2)];
        us4 h; h.x = f2bf(v.x); h.y = f2bf(v.y); h.z = f2bf(v.z); h.w = f2bf(v.w);
        *(us4*)&wS[m * WSTR + (c4 << 2)] = h;
      }
      __syncthreads();
      for (int ks = 0; ks < BL / 32; ++ks) {
        bf16x8 afr[4];
        for (int mf = 0; mf < 4; ++mf)
          afr[mf] = *(const bf16x8*)&wS[(mf * 16 + arow) * WSTR + ks * 32 + akk];
        const int l0 = lt * BL + ks * 32;
        for (int f = 0; f < 2; ++f) {
          bf16x8 bfr = *(const bf16x8*)&xcp[c * XSTR + l0 + f * 16 + pbase0];
          for (int mf = 0; mf < 4; ++mf)
            acc[mf][f] = __builtin_amdgcn_mfma_f32_16x16x32_bf16(afr[mf], bfr, acc[mf][f], 0, 0, 0);
        }
      }
    }
  }
  const int col = lane & 15;
  const int rb  = (lane >> 4) << 2;
  for (int mf = 0; mf < 4; ++mf)
    for (int f = 0; f < 2; ++f)
      for (int r = 0; r < 4; ++r) {
        int m = mf * 16 + rb + r;
        int k = k0 + wv * 32 + f * 16 + col;
        out[(i * NFEAT + m) * NSYMM + k] = acc[mf][f][r] + bias[m];
      }
}

extern "C" void kernel_launch(void* const* d_in, const int* in_sizes, int n_in,
                              void* d_out, int out_size, void* d_ws, size_t ws_size,
                              hipStream_t stream) {
  const float* x    = (const float*)d_in[0];
  // d_in[1] = symm (cyclic translations by construction) — unused
  const float* ker  = (const float*)d_in[2];
  const float* bias = (const float*)d_in[3];
  float* out = (float*)d_out;

  const size_t w_elems = 4u * 8u * 64u * 128u;            // 262144 (512 KB)
  const size_t x_elems = 64u * 4u * 8u * 2048u;           // 4194304 (8 MB)
  if (ws_size >= (w_elems + x_elems) * sizeof(unsigned short)) {
    unsigned short* wprep  = (unsigned short*)d_ws;
    unsigned short* xshift = wprep + w_elems;
    prep_all<<<dim3(2176), dim3(256), 0, stream>>>(x, ker, wprep, xshift);
    dense_symm_main<<<dim3(512), dim3(256), 0, stream>>>(wprep, xshift, bias, out);
  } else {
    dense_symm_kernel<<<dim3(512), dim3(256), 0, stream>>>(x, ker, bias, out);
  }
}